// Round 4
// baseline (232.683 us; speedup 1.0000x reference)
//
#include <hip/hip_runtime.h>

#define TOTAL 4146
#define TLEN  4096
#define BURN  50
#define NSER  4096
#define LCH   66            // chunk length (even -> compile-time window offsets)
#define NCH   63            // 62 full chunks + 1 short
#define LLAST 54            // 4146 - 62*66
#define WIN   36            // float2 per preload window (72 floats)

// ws layout (floats):
//   Hc[24][NSER]      homogeneous consts: slot k*6+j (j=0..3 T-column rows), +4 = U_k, +5 = V_k
//   R [6][NCH][NSER]  K1 writes (x_end[4], C1o, C2o); K2 overwrites in-place with (x_init[4], w1, w2); K3 reads
// total = (24 + 6*63) * 4096 * 4 B = 6.44 MB

template<int FI>
__device__ __forceinline__ float wget(const float2 (&buf)[WIN]) {
    return (FI & 1) ? buf[FI >> 1].y : buf[FI >> 1].x;
}

// Run LC steps of the ARMA recurrence + ungated double cumsum.
// All indices compile-time after inlining -> registers only.
// Window buf holds noise floats; global step s reads float index OFF+s.
template<int OFF, int LC, bool STORE, int TAU0>
__device__ __forceinline__ void run_chunk(const float2 (&buf)[WIN],
    float (&yh)[4], float (&m)[4], float& w1, float& w2,
    float P0, float P1, float P2, float P3,
    float T0, float T1, float T2, float T3,
    float sg, float cc, int d, float* __restrict__ outp)
{
    #pragma unroll
    for (int s = 0; s < LC; ++s) {
        const int gi = OFF + s;
        const float nt = (gi & 1) ? buf[gi >> 1].y : buf[gi >> 1].x;
        float u = fmaf(T0, m[(s + 3) & 3], nt);
        u = fmaf(T1, m[(s + 2) & 3], u);
        u = fmaf(T2, m[(s + 1) & 3], u);
        u = fmaf(T3, m[(s + 0) & 3], u);
        float yv = fmaf(sg, u, cc);
        yv = fmaf(P3, yh[(s + 0) & 3], yv);
        yv = fmaf(P2, yh[(s + 1) & 3], yv);
        yv = fmaf(P1, yh[(s + 2) & 3], yv);
        yv = fmaf(P0, yh[(s + 3) & 3], yv);
        yh[s & 3] = yv;
        m[s & 3] = nt;
        w1 += yv;           // pure cumsum level 1
        w2 += w1;           // pure cumsum level 2
        if (STORE) {
            if (s >= TAU0) {
                const float ov = (d == 0) ? yv : ((d == 1) ? w1 : w2);
                outp[s] = ov;
            }
        }
    }
}

__device__ __forceinline__ void load_win(float2 (&buf)[WIN], const float* base) {
    const float2* p = reinterpret_cast<const float2*>(base);  // base is 8B-aligned (row base 8B, even offsets)
    #pragma unroll
    for (int k = 0; k < WIN; ++k) buf[k] = p[k];
}

template<int OFF>
__device__ __forceinline__ void init_eps(const float2 (&buf)[WIN], float (&m)[4]) {
    m[3] = wget<OFF - 1>(buf);   // raw noise n_{t0-1} (sigma folded into step via sg*u)
    m[2] = wget<OFF - 2>(buf);
    m[1] = wget<OFF - 3>(buf);
    m[0] = wget<OFF - 4>(buf);
}

// ---- K1: per-chunk particular solutions (zero y-init) + homogeneous basis consts
__global__ __launch_bounds__(256, 4) void k1_particular(
    const float* __restrict__ phi_, const float* __restrict__ theta_,
    const float* __restrict__ icept_, const float* __restrict__ sigma_,
    const float* __restrict__ noise_, float* __restrict__ ws)
{
    float* Hc = ws;
    float* R  = ws + 24 * NSER;
    const size_t RSTR = (size_t)NCH * NSER;

    if (blockIdx.x >= 62 * 16) {
        // homogeneous basis: 16384 threads = 4 basis * 4096 series
        const int tid = (blockIdx.x - 62 * 16) * 256 + threadIdx.x;
        const int k = tid >> 12;           // basis index 0..3 (unit init at y_{t-1-k})
        const int i = tid & (NSER - 1);
        const float P0 = phi_[i*4+0], P1 = phi_[i*4+1], P2 = phi_[i*4+2], P3 = phi_[i*4+3];
        float yh[4];
        yh[0] = (k == 3) ? 1.f : 0.f;      // yh[3] holds y_{t-1}
        yh[1] = (k == 2) ? 1.f : 0.f;
        yh[2] = (k == 1) ? 1.f : 0.f;
        yh[3] = (k == 0) ? 1.f : 0.f;
        float c1 = 0.f, c2 = 0.f;
        #pragma unroll
        for (int s = 0; s < LCH; ++s) {
            float yv = P3 * yh[(s + 0) & 3];
            yv = fmaf(P2, yh[(s + 1) & 3], yv);
            yv = fmaf(P1, yh[(s + 2) & 3], yv);
            yv = fmaf(P0, yh[(s + 3) & 3], yv);
            yh[s & 3] = yv;
            c1 += yv; c2 += c1;
        }
        // final state perm: (LCH-1)&3 == 1 -> recent..recent-3 = yh[1],yh[0],yh[3],yh[2]
        Hc[(k*6 + 0) * NSER + i] = yh[1];
        Hc[(k*6 + 1) * NSER + i] = yh[0];
        Hc[(k*6 + 2) * NSER + i] = yh[3];
        Hc[(k*6 + 3) * NSER + i] = yh[2];
        Hc[(k*6 + 4) * NSER + i] = c1;
        Hc[(k*6 + 5) * NSER + i] = c2;
        return;
    }

    const int c = blockIdx.x >> 4;                       // 0..61 (last chunk not needed)
    const int i = ((blockIdx.x & 15) << 8) + threadIdx.x;
    const float P0 = phi_[i*4+0], P1 = phi_[i*4+1], P2 = phi_[i*4+2], P3 = phi_[i*4+3];
    const float T0 = theta_[i*4+0], T1 = theta_[i*4+1], T2 = theta_[i*4+2], T3 = theta_[i*4+3];
    const float cc = icept_[i];
    const float sg = sigma_[i];
    const float* nrow = noise_ + (size_t)i * TOTAL;
    const int t0 = c * LCH;

    float2 buf[WIN];
    float yh[4] = {0.f, 0.f, 0.f, 0.f};
    float m[4]  = {0.f, 0.f, 0.f, 0.f};
    float w1 = 0.f, w2 = 0.f;

    if (c == 0) {
        load_win(buf, nrow);
        run_chunk<0, LCH, false, 0>(buf, yh, m, w1, w2, P0,P1,P2,P3, T0,T1,T2,T3, sg, cc, 0, nullptr);
    } else {
        load_win(buf, nrow + t0 - 4);                    // t0 even -> 8B-aligned
        init_eps<4>(buf, m);
        run_chunk<4, LCH, false, 0>(buf, yh, m, w1, w2, P0,P1,P2,P3, T0,T1,T2,T3, sg, cc, 0, nullptr);
    }
    float* p = R + (size_t)c * NSER + i;
    p[0*RSTR] = yh[1];   // x_end[0] = y_{t0+65}
    p[1*RSTR] = yh[0];
    p[2*RSTR] = yh[3];
    p[3*RSTR] = yh[2];
    p[4*RSTR] = w1;      // C1o
    p[5*RSTR] = w2;      // C2o
}

// ---- K2: per-series 63-chunk affine scan of (x[4], w1, w2); overwrites R with init states
__global__ __launch_bounds__(256) void k2_scan(float* __restrict__ ws)
{
    float* Hc = ws;
    float* R  = ws + 24 * NSER;
    const size_t RSTR = (size_t)NCH * NSER;
    const int i = blockIdx.x * 256 + threadIdx.x;

    float T[16], U[4], V[4];
    #pragma unroll
    for (int k = 0; k < 4; ++k) {
        T[k*4+0] = Hc[(k*6 + 0) * NSER + i];
        T[k*4+1] = Hc[(k*6 + 1) * NSER + i];
        T[k*4+2] = Hc[(k*6 + 2) * NSER + i];
        T[k*4+3] = Hc[(k*6 + 3) * NSER + i];
        U[k]     = Hc[(k*6 + 4) * NSER + i];
        V[k]     = Hc[(k*6 + 5) * NSER + i];
    }

    float x0 = 0.f, x1 = 0.f, x2 = 0.f, x3 = 0.f, w1 = 0.f, w2 = 0.f;
    for (int c = 0; c < NCH; ++c) {
        float* p = R + (size_t)c * NSER + i;
        float r0, r1, r2, r3, r4, r5;
        const bool upd = (c < NCH - 1);
        if (upd) {
            r0 = p[0*RSTR]; r1 = p[1*RSTR]; r2 = p[2*RSTR];
            r3 = p[3*RSTR]; r4 = p[4*RSTR]; r5 = p[5*RSTR];
        }
        // store init state for this chunk (in-place)
        p[0*RSTR] = x0; p[1*RSTR] = x1; p[2*RSTR] = x2;
        p[3*RSTR] = x3; p[4*RSTR] = w1; p[5*RSTR] = w2;
        if (upd) {
            float C1 = r4;
            C1 = fmaf(U[0], x0, C1); C1 = fmaf(U[1], x1, C1);
            C1 = fmaf(U[2], x2, C1); C1 = fmaf(U[3], x3, C1);
            float C2 = r5;
            C2 = fmaf(V[0], x0, C2); C2 = fmaf(V[1], x1, C2);
            C2 = fmaf(V[2], x2, C2); C2 = fmaf(V[3], x3, C2);
            float n0 = r0, n1 = r1, n2 = r2, n3 = r3;
            n0 = fmaf(T[0],  x0, n0); n0 = fmaf(T[4],  x1, n0); n0 = fmaf(T[8],  x2, n0); n0 = fmaf(T[12], x3, n0);
            n1 = fmaf(T[1],  x0, n1); n1 = fmaf(T[5],  x1, n1); n1 = fmaf(T[9],  x2, n1); n1 = fmaf(T[13], x3, n1);
            n2 = fmaf(T[2],  x0, n2); n2 = fmaf(T[6],  x1, n2); n2 = fmaf(T[10], x2, n2); n2 = fmaf(T[14], x3, n2);
            n3 = fmaf(T[3],  x0, n3); n3 = fmaf(T[7],  x1, n3); n3 = fmaf(T[11], x2, n3); n3 = fmaf(T[15], x3, n3);
            w2 = fmaf((float)LCH, w1, w2 + C2);   // uses OLD w1
            w1 = w1 + C1;
            x0 = n0; x1 = n1; x2 = n2; x3 = n3;
        }
    }
}

// ---- K3: rerun each chunk with correct init state, write selected output
__global__ __launch_bounds__(256, 4) void k3_final(
    const float* __restrict__ phi_, const float* __restrict__ theta_,
    const float* __restrict__ icept_, const float* __restrict__ sigma_,
    const float* __restrict__ noise_, const int* __restrict__ dvals_,
    const float* __restrict__ ws, float* __restrict__ out_)
{
    const float* R = ws + 24 * NSER;
    const size_t RSTR = (size_t)NCH * NSER;
    const int c = blockIdx.x >> 4;                       // 0..62
    const int i = ((blockIdx.x & 15) << 8) + threadIdx.x;
    const float P0 = phi_[i*4+0], P1 = phi_[i*4+1], P2 = phi_[i*4+2], P3 = phi_[i*4+3];
    const float T0 = theta_[i*4+0], T1 = theta_[i*4+1], T2 = theta_[i*4+2], T3 = theta_[i*4+3];
    const float cc = icept_[i];
    const float sg = sigma_[i];
    const int   d  = dvals_[i];
    const float* nrow = noise_ + (size_t)i * TOTAL;
    const int t0 = c * LCH;

    const float* p = R + (size_t)c * NSER + i;
    float yh[4], m[4] = {0.f, 0.f, 0.f, 0.f};
    yh[3] = p[0*RSTR];   // y_{t0-1}
    yh[2] = p[1*RSTR];
    yh[1] = p[2*RSTR];
    yh[0] = p[3*RSTR];
    float w1 = p[4*RSTR];
    float w2 = p[5*RSTR];

    float* outp = out_ + (size_t)i * TLEN + (t0 - BURN); // s>=TAU0 keeps stores in-bounds

    float2 buf[WIN];
    if (c == 0) {
        load_win(buf, nrow);
        run_chunk<0, LCH, true, BURN>(buf, yh, m, w1, w2, P0,P1,P2,P3, T0,T1,T2,T3, sg, cc, d, outp);
    } else if (c == NCH - 1) {
        load_win(buf, nrow + (TOTAL - 2 * WIN));         // 4074, even; OFF = 4092-4074 = 18
        init_eps<18>(buf, m);
        run_chunk<18, LLAST, true, 0>(buf, yh, m, w1, w2, P0,P1,P2,P3, T0,T1,T2,T3, sg, cc, d, outp);
    } else {
        load_win(buf, nrow + t0 - 4);
        init_eps<4>(buf, m);
        run_chunk<4, LCH, true, 0>(buf, yh, m, w1, w2, P0,P1,P2,P3, T0,T1,T2,T3, sg, cc, d, outp);
    }
}

extern "C" void kernel_launch(void* const* d_in, const int* in_sizes, int n_in,
                              void* d_out, int out_size, void* d_ws, size_t ws_size,
                              hipStream_t stream)
{
    const float* phi   = (const float*)d_in[0];
    const float* theta = (const float*)d_in[1];
    const float* icept = (const float*)d_in[2];
    const float* sigma = (const float*)d_in[3];
    const float* noise = (const float*)d_in[4];
    const int*   dvals = (const int*)d_in[5];
    float* out = (float*)d_out;
    float* ws  = (float*)d_ws;   // needs 6.44 MB

    // K1: 62 chunk-blocks*16 + 64 homogeneous blocks
    k1_particular<<<dim3(62 * 16 + 64), dim3(256), 0, stream>>>(phi, theta, icept, sigma, noise, ws);
    // K2: per-series scan
    k2_scan<<<dim3(16), dim3(256), 0, stream>>>(ws);
    // K3: 63 chunks * 16 blocks
    k3_final<<<dim3(63 * 16), dim3(256), 0, stream>>>(phi, theta, icept, sigma, noise, dvals, ws, out);
}

// Round 7
// 182.771 us; speedup vs baseline: 1.2731x; 1.2731x over previous
//
#include <hip/hip_runtime.h>

#define TOTAL 4146
#define TLEN  4096
#define BURN  50
#define NSER  4096
#define LCH   66            // chunk length
#define NCH   63            // 62 full chunks + 1 short
#define LLAST 54            // 4146 - 62*66
#define PADF  73            // LDS row stride in floats (73 = 2-way bank alias, free)

// ws layout (floats):
//   Hc[24][NSER]      homogeneous consts: slot k*6+j (j=0..3 T-column rows), +4 = U_k, +5 = V_k
//   R [6][NCH][NSER]  K1 writes (x_end[4], C1o, C2o); K2 overwrites in-place with (x_init[4], w1, w2); K3 reads
// total = (24 + 6*63) * 4096 * 4 B = 6.44 MB

// ARMA steps + ungated double cumsum, reading noise from the thread's LDS row.
// STORE variant overwrites window slot s (always at-or-behind the read
// frontier OFF+s; read precedes write within an iteration) with the
// d-selected output value. Arithmetic order identical to the round-4
// passing kernel (absmax = 1 ULP).
template<int OFF, int LC, bool STORE>
__device__ __forceinline__ void run_chunk_lds(float* rowp,
    float (&yh)[4], float (&m)[4], float& w1, float& w2,
    float P0, float P1, float P2, float P3,
    float T0, float T1, float T2, float T3,
    float sg, float cc, int d)
{
    #pragma unroll
    for (int s = 0; s < LC; ++s) {
        const float nt = rowp[OFF + s];
        float u = fmaf(T0, m[(s + 3) & 3], nt);
        u = fmaf(T1, m[(s + 2) & 3], u);
        u = fmaf(T2, m[(s + 1) & 3], u);
        u = fmaf(T3, m[(s + 0) & 3], u);
        float yv = fmaf(sg, u, cc);
        yv = fmaf(P3, yh[(s + 0) & 3], yv);
        yv = fmaf(P2, yh[(s + 1) & 3], yv);
        yv = fmaf(P1, yh[(s + 2) & 3], yv);
        yv = fmaf(P0, yh[(s + 3) & 3], yv);
        yh[s & 3] = yv;
        m[s & 3] = nt;
        w1 += yv;           // pure cumsum level 1
        w2 += w1;           // pure cumsum level 2
        if (STORE) {
            const float ov = (d == 0) ? yv : ((d == 1) ? w1 : w2);
            rowp[s] = ov;   // in-place out staging (slot s already consumed)
        }
    }
}

// Coalesced stage of this block's 256 noise windows into lds[256][PADF].
// Wave w stages rows [w*64, w*64+64); per row lanes 0..35 load contiguous
// float2 (288 B coalesced) and scatter to LDS as two b32 writes.
__device__ __forceinline__ void stage_noise(float* lds, const float* noise_,
                                            int i0, int w, int lane, int tbase)
{
    const float* g0 = noise_ + (size_t)(i0 + (w << 6)) * TOTAL + tbase;
    float* l0 = lds + (w << 6) * PADF;
    if (lane < 36) {
        for (int rr = 0; rr < 64; ++rr) {
            float2 v = *reinterpret_cast<const float2*>(g0 + (size_t)rr * TOTAL + (lane << 1));
            l0[rr * PADF + (lane << 1)]     = v.x;
            l0[rr * PADF + (lane << 1) + 1] = v.y;
        }
    }
}

// ---- K1: per-chunk particular solutions (zero y-init) + homogeneous basis consts
__global__ __launch_bounds__(256, 2) void k1_particular(
    const float* __restrict__ phi_, const float* __restrict__ theta_,
    const float* __restrict__ icept_, const float* __restrict__ sigma_,
    const float* __restrict__ noise_, float* __restrict__ ws)
{
    __shared__ float lds[256 * PADF];
    float* Hc = ws;
    float* R  = ws + 24 * NSER;
    const size_t RSTR = (size_t)NCH * NSER;

    if (blockIdx.x >= 62 * 16) {
        // homogeneous basis: 16384 threads = 4 basis * 4096 series (no LDS use)
        const int tid = (blockIdx.x - 62 * 16) * 256 + threadIdx.x;
        const int k = tid >> 12;           // basis index 0..3 (unit init at y_{t-1-k})
        const int i = tid & (NSER - 1);
        const float P0 = phi_[i*4+0], P1 = phi_[i*4+1], P2 = phi_[i*4+2], P3 = phi_[i*4+3];
        float yh[4];
        yh[0] = (k == 3) ? 1.f : 0.f;      // yh[3] holds y_{t-1}
        yh[1] = (k == 2) ? 1.f : 0.f;
        yh[2] = (k == 1) ? 1.f : 0.f;
        yh[3] = (k == 0) ? 1.f : 0.f;
        float c1 = 0.f, c2 = 0.f;
        #pragma unroll
        for (int s = 0; s < LCH; ++s) {
            float yv = P3 * yh[(s + 0) & 3];
            yv = fmaf(P2, yh[(s + 1) & 3], yv);
            yv = fmaf(P1, yh[(s + 2) & 3], yv);
            yv = fmaf(P0, yh[(s + 3) & 3], yv);
            yh[s & 3] = yv;
            c1 += yv; c2 += c1;
        }
        // final state perm: (LCH-1)&3 == 1 -> recent..recent-3 = yh[1],yh[0],yh[3],yh[2]
        Hc[(k*6 + 0) * NSER + i] = yh[1];
        Hc[(k*6 + 1) * NSER + i] = yh[0];
        Hc[(k*6 + 2) * NSER + i] = yh[3];
        Hc[(k*6 + 3) * NSER + i] = yh[2];
        Hc[(k*6 + 4) * NSER + i] = c1;
        Hc[(k*6 + 5) * NSER + i] = c2;
        return;
    }

    const int c    = blockIdx.x >> 4;                  // 0..61 (last chunk not needed)
    const int i0   = (blockIdx.x & 15) << 8;
    const int tid  = threadIdx.x;
    const int w    = tid >> 6, lane = tid & 63;
    const int i    = i0 + tid;
    const int t0   = c * LCH;
    const int tbase = (c == 0) ? 0 : (t0 - 4);

    // issue param loads before staging (overlap latency)
    const float P0 = phi_[i*4+0], P1 = phi_[i*4+1], P2 = phi_[i*4+2], P3 = phi_[i*4+3];
    const float T0 = theta_[i*4+0], T1 = theta_[i*4+1], T2 = theta_[i*4+2], T3 = theta_[i*4+3];
    const float cc = icept_[i];
    const float sg = sigma_[i];

    stage_noise(lds, noise_, i0, w, lane, tbase);
    __syncthreads();

    float* myrow = lds + tid * PADF;
    float yh[4] = {0.f, 0.f, 0.f, 0.f};
    float m[4]  = {0.f, 0.f, 0.f, 0.f};
    float w1 = 0.f, w2 = 0.f;

    if (c == 0) {
        run_chunk_lds<0, LCH, false>(myrow, yh, m, w1, w2, P0,P1,P2,P3, T0,T1,T2,T3, sg, cc, 0);
    } else {
        m[3] = myrow[3]; m[2] = myrow[2]; m[1] = myrow[1]; m[0] = myrow[0];  // eps init (raw noise)
        run_chunk_lds<4, LCH, false>(myrow, yh, m, w1, w2, P0,P1,P2,P3, T0,T1,T2,T3, sg, cc, 0);
    }
    float* p = R + (size_t)c * NSER + i;
    p[0*RSTR] = yh[1];   // x_end[0] = y_{t0+65}
    p[1*RSTR] = yh[0];
    p[2*RSTR] = yh[3];
    p[3*RSTR] = yh[2];
    p[4*RSTR] = w1;      // C1o
    p[5*RSTR] = w2;      // C2o
}

// ---- K2: per-series 63-chunk affine scan of (x[4], w1, w2); overwrites R with init states.
// 3-deep prefetch pipeline hides the ~400cy L2/L3 latency of the serial chain.
__global__ __launch_bounds__(256) void k2_scan(float* __restrict__ ws)
{
    float* Hc = ws;
    float* R  = ws + 24 * NSER;
    const size_t RSTR = (size_t)NCH * NSER;
    const int i = blockIdx.x * 256 + threadIdx.x;

    float T[16], U[4], V[4];
    #pragma unroll
    for (int k = 0; k < 4; ++k) {
        T[k*4+0] = Hc[(k*6 + 0) * NSER + i];
        T[k*4+1] = Hc[(k*6 + 1) * NSER + i];
        T[k*4+2] = Hc[(k*6 + 2) * NSER + i];
        T[k*4+3] = Hc[(k*6 + 3) * NSER + i];
        U[k]     = Hc[(k*6 + 4) * NSER + i];
        V[k]     = Hc[(k*6 + 5) * NSER + i];
    }

    float* Rb = R + i;   // element [j][c] at Rb[j*RSTR + c*NSER]

    float x0 = 0.f, x1 = 0.f, x2 = 0.f, x3 = 0.f, w1 = 0.f, w2 = 0.f;
    int cc = 0;

#define K2_LOADSET(S0,S1,S2,S3,S4,S5, cidx)                                   \
    { const float* pq = Rb + (size_t)(cidx) * NSER;                           \
      S0 = pq[0*RSTR]; S1 = pq[1*RSTR]; S2 = pq[2*RSTR];                      \
      S3 = pq[3*RSTR]; S4 = pq[4*RSTR]; S5 = pq[5*RSTR]; }

    float A0,A1,A2,A3,A4,A5, B0,B1,B2,B3,B4,B5, C0,C1,C2,C3,C4,C5;
    K2_LOADSET(A0,A1,A2,A3,A4,A5, 0)
    K2_LOADSET(B0,B1,B2,B3,B4,B5, 1)
    K2_LOADSET(C0,C1,C2,C3,C4,C5, 2)

    // Prefetch index clamped to 61 (valid memory); clamped loads are never
    // consumed. r[61] is consumed at iter 61 but was prefetched at iter 58,
    // before z_61 overwrites slot 61 -> no WAR hazard on real data.
#define K2_ITER(S0,S1,S2,S3,S4,S5)                                            \
    {                                                                         \
        float* q = R + (size_t)cc * NSER + i;                                 \
        q[0*RSTR] = x0; q[1*RSTR] = x1; q[2*RSTR] = x2;                       \
        q[3*RSTR] = x3; q[4*RSTR] = w1; q[5*RSTR] = w2;                       \
        if (cc < NCH - 1) {                                                   \
            float C1v = S4;                                                   \
            C1v = fmaf(U[0], x0, C1v); C1v = fmaf(U[1], x1, C1v);             \
            C1v = fmaf(U[2], x2, C1v); C1v = fmaf(U[3], x3, C1v);             \
            float C2v = S5;                                                   \
            C2v = fmaf(V[0], x0, C2v); C2v = fmaf(V[1], x1, C2v);             \
            C2v = fmaf(V[2], x2, C2v); C2v = fmaf(V[3], x3, C2v);             \
            float n0 = S0, n1 = S1, n2 = S2, n3 = S3;                         \
            n0 = fmaf(T[0],  x0, n0); n0 = fmaf(T[4],  x1, n0);               \
            n0 = fmaf(T[8],  x2, n0); n0 = fmaf(T[12], x3, n0);               \
            n1 = fmaf(T[1],  x0, n1); n1 = fmaf(T[5],  x1, n1);               \
            n1 = fmaf(T[9],  x2, n1); n1 = fmaf(T[13], x3, n1);               \
            n2 = fmaf(T[2],  x0, n2); n2 = fmaf(T[6],  x1, n2);               \
            n2 = fmaf(T[10], x2, n2); n2 = fmaf(T[14], x3, n2);               \
            n3 = fmaf(T[3],  x0, n3); n3 = fmaf(T[7],  x1, n3);               \
            n3 = fmaf(T[11], x2, n3); n3 = fmaf(T[15], x3, n3);               \
            w2 = fmaf((float)LCH, w1, w2 + C2v);   /* uses OLD w1 */          \
            w1 = w1 + C1v;                                                    \
            x0 = n0; x1 = n1; x2 = n2; x3 = n3;                               \
            int cl = cc + 3; if (cl > 61) cl = 61;                            \
            K2_LOADSET(S0,S1,S2,S3,S4,S5, cl)                                 \
        }                                                                     \
        ++cc;                                                                 \
    }

    #pragma unroll 1
    for (int g = 0; g < 21; ++g) {       // 21*3 = 63 iterations, cc = 0..62
        K2_ITER(A0,A1,A2,A3,A4,A5)
        K2_ITER(B0,B1,B2,B3,B4,B5)
        K2_ITER(C0,C1,C2,C3,C4,C5)
    }
#undef K2_ITER
#undef K2_LOADSET
}

// ---- K3: rerun each chunk with correct init state; stage outputs in LDS
// (in-place in the noise window) and flush with coalesced row-major stores.
__global__ __launch_bounds__(256, 2) void k3_final(
    const float* __restrict__ phi_, const float* __restrict__ theta_,
    const float* __restrict__ icept_, const float* __restrict__ sigma_,
    const float* __restrict__ noise_, const int* __restrict__ dvals_,
    const float* __restrict__ ws, float* __restrict__ out_)
{
    __shared__ float lds[256 * PADF];
    const float* R = ws + 24 * NSER;
    const size_t RSTR = (size_t)NCH * NSER;
    const int c    = blockIdx.x >> 4;                  // 0..62
    const int i0   = (blockIdx.x & 15) << 8;
    const int tid  = threadIdx.x;
    const int w    = tid >> 6, lane = tid & 63;
    const int i    = i0 + tid;
    const int t0   = c * LCH;
    const int tbase = (c == 0) ? 0 : ((c == NCH - 1) ? (TOTAL - 72) : (t0 - 4));

    // issue param + state loads before staging (overlap latency)
    const float P0 = phi_[i*4+0], P1 = phi_[i*4+1], P2 = phi_[i*4+2], P3 = phi_[i*4+3];
    const float T0 = theta_[i*4+0], T1 = theta_[i*4+1], T2 = theta_[i*4+2], T3 = theta_[i*4+3];
    const float cc = icept_[i];
    const float sg = sigma_[i];
    const int   d  = dvals_[i];
    const float* p = R + (size_t)c * NSER + i;
    float yh[4], m[4] = {0.f, 0.f, 0.f, 0.f};
    yh[3] = p[0*RSTR];   // y_{t0-1}
    yh[2] = p[1*RSTR];
    yh[1] = p[2*RSTR];
    yh[0] = p[3*RSTR];
    float w1 = p[4*RSTR];
    float w2 = p[5*RSTR];

    stage_noise(lds, noise_, i0, w, lane, tbase);
    __syncthreads();

    float* myrow = lds + tid * PADF;
    if (c == 0) {
        run_chunk_lds<0, LCH, true>(myrow, yh, m, w1, w2, P0,P1,P2,P3, T0,T1,T2,T3, sg, cc, d);
    } else if (c == NCH - 1) {
        m[3] = myrow[17]; m[2] = myrow[16]; m[1] = myrow[15]; m[0] = myrow[14];
        run_chunk_lds<18, LLAST, true>(myrow, yh, m, w1, w2, P0,P1,P2,P3, T0,T1,T2,T3, sg, cc, d);
    } else {
        m[3] = myrow[3]; m[2] = myrow[2]; m[1] = myrow[1]; m[0] = myrow[0];
        run_chunk_lds<4, LCH, true>(myrow, yh, m, w1, w2, P0,P1,P2,P3, T0,T1,T2,T3, sg, cc, d);
    }

    __syncthreads();

    // flush: window slot j -> out col t0 - 50 + j, for j in [lo, hi)
    const int lo = (c == 0) ? BURN : 0;
    const int hi = (c == NCH - 1) ? LLAST : LCH;
    const int gb = t0 - BURN;
    const int ncols = hi - lo;
    if (ncols >= 64) {                       // middle chunks: 66 cols
        for (int rr = 0; rr < 64; ++rr) {
            const int r = (w << 6) + rr;
            const float v = lds[r * PADF + lane];           // lo == 0
            out_[(size_t)(i0 + r) * TLEN + gb + lane] = v;  // coalesced 256 B
        }
        #pragma unroll
        for (int h = 0; h < 2; ++h) {        // leftover cols 64,65 packed
            const int r = (w << 6) + (h << 5) + (lane >> 1);
            const int j = 64 + (lane & 1);
            const float v = lds[r * PADF + j];
            out_[(size_t)(i0 + r) * TLEN + gb + j] = v;
        }
    } else {                                 // c==0 (16 cols) or c==62 (54 cols)
        for (int rr = 0; rr < 64; ++rr) {
            const int r = (w << 6) + rr;
            if (lane < ncols) {
                const float v = lds[r * PADF + lo + lane];
                out_[(size_t)(i0 + r) * TLEN + gb + lo + lane] = v;
            }
        }
    }
}

extern "C" void kernel_launch(void* const* d_in, const int* in_sizes, int n_in,
                              void* d_out, int out_size, void* d_ws, size_t ws_size,
                              hipStream_t stream)
{
    const float* phi   = (const float*)d_in[0];
    const float* theta = (const float*)d_in[1];
    const float* icept = (const float*)d_in[2];
    const float* sigma = (const float*)d_in[3];
    const float* noise = (const float*)d_in[4];
    const int*   dvals = (const int*)d_in[5];
    float* out = (float*)d_out;
    float* ws  = (float*)d_ws;   // needs 6.44 MB

    // K1: 62 chunk-blocks*16 + 64 homogeneous blocks
    k1_particular<<<dim3(62 * 16 + 64), dim3(256), 0, stream>>>(phi, theta, icept, sigma, noise, ws);
    // K2: per-series scan
    k2_scan<<<dim3(16), dim3(256), 0, stream>>>(ws);
    // K3: 63 chunks * 16 blocks
    k3_final<<<dim3(63 * 16), dim3(256), 0, stream>>>(phi, theta, icept, sigma, noise, dvals, ws, out);
}

// Round 10
// 179.228 us; speedup vs baseline: 1.2983x; 1.0198x over previous
//
#include <hip/hip_runtime.h>

#define TOTAL 4146
#define TLEN  4096
#define BURN  50
#define NSER  4096
#define LCH   66            // chunk length
#define NCH   63            // 62 full chunks + 1 short
#define LLAST 54            // 4146 - 62*66
#define PADF  73            // LDS row stride in floats (73 = 2-way bank alias, free)

// ws layout (floats):
//   Hc[24][NSER]      homogeneous consts: slot k*6+j (j=0..3 T-column rows), +4 = U_k, +5 = V_k
//   R [6][NCH][NSER]  K1 writes (x_end[4], C1o, C2o); K2 overwrites in-place with (x_init[4], w1, w2); K3 reads
// total = (24 + 6*63) * 4096 * 4 B = 6.44 MB

// ---- async global->LDS staging (no VGPR round-trip).
// HW semantics: LDS dest = wave-uniform base + lane*4; global src per-lane.
__device__ __forceinline__ void gload_lds4(const float* g, float* l) {
    __builtin_amdgcn_global_load_lds(
        (const __attribute__((address_space(1))) void*)g,
        (__attribute__((address_space(3))) void*)l, 4, 0, 0);
}

// Stage this block's 256 noise windows (72 floats each) into lds[256][PADF].
// Wave w stages rows [w*64, w*64+64): per row one 64-lane async load
// (floats 0..63) + one 8-lane tail load (floats 64..71).
__device__ __forceinline__ void stage_noise(float* lds, const float* noise_,
                                            int i0, int w, int lane, int tbase)
{
    const int r0 = w << 6;
    const float* g0 = noise_ + (size_t)(i0 + r0) * TOTAL + tbase;
    float* l0 = lds + r0 * PADF;
    for (int rr = 0; rr < 64; ++rr)
        gload_lds4(g0 + (size_t)rr * TOTAL + lane, l0 + rr * PADF);
    if (lane < 8) {
        for (int rr = 0; rr < 64; ++rr)
            gload_lds4(g0 + (size_t)rr * TOTAL + 64 + lane, l0 + rr * PADF + 64);
    }
    // __syncthreads() at call site drains vmcnt (incl. global_load_lds queue)
}

// ARMA steps + ungated double cumsum, reading noise from the thread's LDS row.
// STORE variant overwrites window slot s (read of OFF+s precedes write of s
// within an iteration, OFF>=0 -> safe) with the d-selected output value.
// Arithmetic order identical to the round-4/7 passing kernels (absmax 1 ULP).
template<int OFF, int LC, bool STORE>
__device__ __forceinline__ void run_chunk_lds(float* rowp,
    float (&yh)[4], float (&m)[4], float& w1, float& w2,
    float P0, float P1, float P2, float P3,
    float T0, float T1, float T2, float T3,
    float sg, float cc, int d)
{
    #pragma unroll
    for (int s = 0; s < LC; ++s) {
        const float nt = rowp[OFF + s];
        float u = fmaf(T0, m[(s + 3) & 3], nt);
        u = fmaf(T1, m[(s + 2) & 3], u);
        u = fmaf(T2, m[(s + 1) & 3], u);
        u = fmaf(T3, m[(s + 0) & 3], u);
        float yv = fmaf(sg, u, cc);
        yv = fmaf(P3, yh[(s + 0) & 3], yv);
        yv = fmaf(P2, yh[(s + 1) & 3], yv);
        yv = fmaf(P1, yh[(s + 2) & 3], yv);
        yv = fmaf(P0, yh[(s + 3) & 3], yv);
        yh[s & 3] = yv;
        m[s & 3] = nt;
        w1 += yv;           // pure cumsum level 1
        w2 += w1;           // pure cumsum level 2
        if (STORE) {
            const float ov = (d == 0) ? yv : ((d == 1) ? w1 : w2);
            rowp[s] = ov;   // in-place out staging (slot s already consumed)
        }
    }
}

// ---- K1: per-chunk particular solutions (zero y-init) + homogeneous basis consts
__global__ __launch_bounds__(256, 2) void k1_particular(
    const float* __restrict__ phi_, const float* __restrict__ theta_,
    const float* __restrict__ icept_, const float* __restrict__ sigma_,
    const float* __restrict__ noise_, float* __restrict__ ws)
{
    __shared__ float lds[256 * PADF];
    float* Hc = ws;
    float* R  = ws + 24 * NSER;
    const size_t RSTR = (size_t)NCH * NSER;

    if (blockIdx.x >= 62 * 16) {
        // homogeneous basis: 16384 threads = 4 basis * 4096 series (no LDS use)
        const int tid = (blockIdx.x - 62 * 16) * 256 + threadIdx.x;
        const int k = tid >> 12;           // basis index 0..3 (unit init at y_{t-1-k})
        const int i = tid & (NSER - 1);
        const float P0 = phi_[i*4+0], P1 = phi_[i*4+1], P2 = phi_[i*4+2], P3 = phi_[i*4+3];
        float yh[4];
        yh[0] = (k == 3) ? 1.f : 0.f;      // yh[3] holds y_{t-1}
        yh[1] = (k == 2) ? 1.f : 0.f;
        yh[2] = (k == 1) ? 1.f : 0.f;
        yh[3] = (k == 0) ? 1.f : 0.f;
        float c1 = 0.f, c2 = 0.f;
        #pragma unroll
        for (int s = 0; s < LCH; ++s) {
            float yv = P3 * yh[(s + 0) & 3];
            yv = fmaf(P2, yh[(s + 1) & 3], yv);
            yv = fmaf(P1, yh[(s + 2) & 3], yv);
            yv = fmaf(P0, yh[(s + 3) & 3], yv);
            yh[s & 3] = yv;
            c1 += yv; c2 += c1;
        }
        // final state perm: (LCH-1)&3 == 1 -> recent..recent-3 = yh[1],yh[0],yh[3],yh[2]
        Hc[(k*6 + 0) * NSER + i] = yh[1];
        Hc[(k*6 + 1) * NSER + i] = yh[0];
        Hc[(k*6 + 2) * NSER + i] = yh[3];
        Hc[(k*6 + 3) * NSER + i] = yh[2];
        Hc[(k*6 + 4) * NSER + i] = c1;
        Hc[(k*6 + 5) * NSER + i] = c2;
        return;
    }

    const int c    = blockIdx.x >> 4;                  // 0..61 (last chunk not needed)
    const int i0   = (blockIdx.x & 15) << 8;
    const int tid  = threadIdx.x;
    const int w    = tid >> 6, lane = tid & 63;
    const int i    = i0 + tid;
    const int t0   = c * LCH;
    const int tbase = (c == 0) ? 0 : (t0 - 4);

    stage_noise(lds, noise_, i0, w, lane, tbase);   // async, drained by barrier

    // param loads overlap the async staging
    const float P0 = phi_[i*4+0], P1 = phi_[i*4+1], P2 = phi_[i*4+2], P3 = phi_[i*4+3];
    const float T0 = theta_[i*4+0], T1 = theta_[i*4+1], T2 = theta_[i*4+2], T3 = theta_[i*4+3];
    const float cc = icept_[i];
    const float sg = sigma_[i];

    __syncthreads();

    float* myrow = lds + tid * PADF;
    float yh[4] = {0.f, 0.f, 0.f, 0.f};
    float m[4]  = {0.f, 0.f, 0.f, 0.f};
    float w1 = 0.f, w2 = 0.f;

    if (c == 0) {
        run_chunk_lds<0, LCH, false>(myrow, yh, m, w1, w2, P0,P1,P2,P3, T0,T1,T2,T3, sg, cc, 0);
    } else {
        m[3] = myrow[3]; m[2] = myrow[2]; m[1] = myrow[1]; m[0] = myrow[0];  // eps init (raw noise)
        run_chunk_lds<4, LCH, false>(myrow, yh, m, w1, w2, P0,P1,P2,P3, T0,T1,T2,T3, sg, cc, 0);
    }
    float* p = R + (size_t)c * NSER + i;
    p[0*RSTR] = yh[1];   // x_end[0] = y_{t0+65}
    p[1*RSTR] = yh[0];
    p[2*RSTR] = yh[3];
    p[3*RSTR] = yh[2];
    p[4*RSTR] = w1;      // C1o
    p[5*RSTR] = w2;      // C2o
}

// ---- K2: per-series 63-chunk affine scan of (x[4], w1, w2); overwrites R with
// init states. 64 blocks x 64 threads (64 CUs, 4x issue BW of 16x256) with
// 4-deep prefetch to hide the serial chain's L2 latency.
__global__ __launch_bounds__(64) void k2_scan(float* __restrict__ ws)
{
    float* Hc = ws;
    float* R  = ws + 24 * NSER;
    const size_t RSTR = (size_t)NCH * NSER;
    const int i = blockIdx.x * 64 + threadIdx.x;

    float T[16], U[4], V[4];
    #pragma unroll
    for (int k = 0; k < 4; ++k) {
        T[k*4+0] = Hc[(k*6 + 0) * NSER + i];
        T[k*4+1] = Hc[(k*6 + 1) * NSER + i];
        T[k*4+2] = Hc[(k*6 + 2) * NSER + i];
        T[k*4+3] = Hc[(k*6 + 3) * NSER + i];
        U[k]     = Hc[(k*6 + 4) * NSER + i];
        V[k]     = Hc[(k*6 + 5) * NSER + i];
    }

    float* Rb = R + i;   // element [j][c] at Rb[j*RSTR + c*NSER]

    float x0 = 0.f, x1 = 0.f, x2 = 0.f, x3 = 0.f, w1 = 0.f, w2 = 0.f;
    int cc = 0;

#define K2_LOADSET(S0,S1,S2,S3,S4,S5, cidx)                                   \
    { const float* pq = Rb + (size_t)(cidx) * NSER;                           \
      S0 = pq[0*RSTR]; S1 = pq[1*RSTR]; S2 = pq[2*RSTR];                      \
      S3 = pq[3*RSTR]; S4 = pq[4*RSTR]; S5 = pq[5*RSTR]; }

    float A0,A1,A2,A3,A4,A5, B0,B1,B2,B3,B4,B5,
          C0,C1,C2,C3,C4,C5, D0,D1,D2,D3,D4,D5;
    K2_LOADSET(A0,A1,A2,A3,A4,A5, 0)
    K2_LOADSET(B0,B1,B2,B3,B4,B5, 1)
    K2_LOADSET(C0,C1,C2,C3,C4,C5, 2)
    K2_LOADSET(D0,D1,D2,D3,D4,D5, 3)

    // Prefetch index clamped to 61 (valid memory); clamped loads are never
    // consumed. Slot 61 is consumed at iter 61, prefetched at iter 57 --
    // before iter 61's store overwrites it -> no WAR hazard.
#define K2_ITER(S0,S1,S2,S3,S4,S5)                                            \
    {                                                                         \
        float* q = R + (size_t)cc * NSER + i;                                 \
        q[0*RSTR] = x0; q[1*RSTR] = x1; q[2*RSTR] = x2;                       \
        q[3*RSTR] = x3; q[4*RSTR] = w1; q[5*RSTR] = w2;                       \
        if (cc < NCH - 1) {                                                   \
            float C1v = S4;                                                   \
            C1v = fmaf(U[0], x0, C1v); C1v = fmaf(U[1], x1, C1v);             \
            C1v = fmaf(U[2], x2, C1v); C1v = fmaf(U[3], x3, C1v);             \
            float C2v = S5;                                                   \
            C2v = fmaf(V[0], x0, C2v); C2v = fmaf(V[1], x1, C2v);             \
            C2v = fmaf(V[2], x2, C2v); C2v = fmaf(V[3], x3, C2v);             \
            float n0 = S0, n1 = S1, n2 = S2, n3 = S3;                         \
            n0 = fmaf(T[0],  x0, n0); n0 = fmaf(T[4],  x1, n0);               \
            n0 = fmaf(T[8],  x2, n0); n0 = fmaf(T[12], x3, n0);               \
            n1 = fmaf(T[1],  x0, n1); n1 = fmaf(T[5],  x1, n1);               \
            n1 = fmaf(T[9],  x2, n1); n1 = fmaf(T[13], x3, n1);               \
            n2 = fmaf(T[2],  x0, n2); n2 = fmaf(T[6],  x1, n2);               \
            n2 = fmaf(T[10], x2, n2); n2 = fmaf(T[14], x3, n2);               \
            n3 = fmaf(T[3],  x0, n3); n3 = fmaf(T[7],  x1, n3);               \
            n3 = fmaf(T[11], x2, n3); n3 = fmaf(T[15], x3, n3);               \
            w2 = fmaf((float)LCH, w1, w2 + C2v);   /* uses OLD w1 */          \
            w1 = w1 + C1v;                                                    \
            x0 = n0; x1 = n1; x2 = n2; x3 = n3;                               \
            int cl = cc + 4; if (cl > 61) cl = 61;                            \
            K2_LOADSET(S0,S1,S2,S3,S4,S5, cl)                                 \
        }                                                                     \
        ++cc;                                                                 \
    }

    #pragma unroll 1
    for (int g = 0; g < 15; ++g) {       // 15*4 = 60 iterations, cc = 0..59
        K2_ITER(A0,A1,A2,A3,A4,A5)
        K2_ITER(B0,B1,B2,B3,B4,B5)
        K2_ITER(C0,C1,C2,C3,C4,C5)
        K2_ITER(D0,D1,D2,D3,D4,D5)
    }
    K2_ITER(A0,A1,A2,A3,A4,A5)           // cc = 60
    K2_ITER(B0,B1,B2,B3,B4,B5)           // cc = 61
    K2_ITER(C0,C1,C2,C3,C4,C5)           // cc = 62 (store-only)
#undef K2_ITER
#undef K2_LOADSET
}

// ---- K3: rerun each chunk with correct init state; stage outputs in LDS
// (in-place in the noise window) and flush with coalesced row-major stores.
__global__ __launch_bounds__(256, 2) void k3_final(
    const float* __restrict__ phi_, const float* __restrict__ theta_,
    const float* __restrict__ icept_, const float* __restrict__ sigma_,
    const float* __restrict__ noise_, const int* __restrict__ dvals_,
    const float* __restrict__ ws, float* __restrict__ out_)
{
    __shared__ float lds[256 * PADF];
    const float* R = ws + 24 * NSER;
    const size_t RSTR = (size_t)NCH * NSER;
    const int c    = blockIdx.x >> 4;                  // 0..62
    const int i0   = (blockIdx.x & 15) << 8;
    const int tid  = threadIdx.x;
    const int w    = tid >> 6, lane = tid & 63;
    const int i    = i0 + tid;
    const int t0   = c * LCH;
    const int tbase = (c == 0) ? 0 : ((c == NCH - 1) ? (TOTAL - 72) : (t0 - 4));

    stage_noise(lds, noise_, i0, w, lane, tbase);   // async, drained by barrier

    // param + state loads overlap the async staging
    const float P0 = phi_[i*4+0], P1 = phi_[i*4+1], P2 = phi_[i*4+2], P3 = phi_[i*4+3];
    const float T0 = theta_[i*4+0], T1 = theta_[i*4+1], T2 = theta_[i*4+2], T3 = theta_[i*4+3];
    const float cc = icept_[i];
    const float sg = sigma_[i];
    const int   d  = dvals_[i];
    const float* p = R + (size_t)c * NSER + i;
    float yh[4], m[4] = {0.f, 0.f, 0.f, 0.f};
    yh[3] = p[0*RSTR];   // y_{t0-1}
    yh[2] = p[1*RSTR];
    yh[1] = p[2*RSTR];
    yh[0] = p[3*RSTR];
    float w1 = p[4*RSTR];
    float w2 = p[5*RSTR];

    __syncthreads();

    float* myrow = lds + tid * PADF;
    if (c == 0) {
        run_chunk_lds<0, LCH, true>(myrow, yh, m, w1, w2, P0,P1,P2,P3, T0,T1,T2,T3, sg, cc, d);
    } else if (c == NCH - 1) {
        m[3] = myrow[17]; m[2] = myrow[16]; m[1] = myrow[15]; m[0] = myrow[14];
        run_chunk_lds<18, LLAST, true>(myrow, yh, m, w1, w2, P0,P1,P2,P3, T0,T1,T2,T3, sg, cc, d);
    } else {
        m[3] = myrow[3]; m[2] = myrow[2]; m[1] = myrow[1]; m[0] = myrow[0];
        run_chunk_lds<4, LCH, true>(myrow, yh, m, w1, w2, P0,P1,P2,P3, T0,T1,T2,T3, sg, cc, d);
    }

    __syncthreads();

    // flush: window slot j -> out col t0 - 50 + j, for j in [lo, hi)
    const int lo = (c == 0) ? BURN : 0;
    const int hi = (c == NCH - 1) ? LLAST : LCH;
    const int gb = t0 - BURN;
    const int ncols = hi - lo;
    if (ncols >= 64) {                       // middle chunks: 66 cols
        for (int rr = 0; rr < 64; ++rr) {
            const int r = (w << 6) + rr;
            const float v = lds[r * PADF + lane];           // lo == 0
            out_[(size_t)(i0 + r) * TLEN + gb + lane] = v;  // coalesced 256 B
        }
        #pragma unroll
        for (int h = 0; h < 2; ++h) {        // leftover cols 64,65 packed
            const int r = (w << 6) + (h << 5) + (lane >> 1);
            const int j = 64 + (lane & 1);
            const float v = lds[r * PADF + j];
            out_[(size_t)(i0 + r) * TLEN + gb + j] = v;
        }
    } else {                                 // c==0 (16 cols) or c==62 (54 cols)
        for (int rr = 0; rr < 64; ++rr) {
            const int r = (w << 6) + rr;
            if (lane < ncols) {
                const float v = lds[r * PADF + lo + lane];
                out_[(size_t)(i0 + r) * TLEN + gb + lo + lane] = v;
            }
        }
    }
}

extern "C" void kernel_launch(void* const* d_in, const int* in_sizes, int n_in,
                              void* d_out, int out_size, void* d_ws, size_t ws_size,
                              hipStream_t stream)
{
    const float* phi   = (const float*)d_in[0];
    const float* theta = (const float*)d_in[1];
    const float* icept = (const float*)d_in[2];
    const float* sigma = (const float*)d_in[3];
    const float* noise = (const float*)d_in[4];
    const int*   dvals = (const int*)d_in[5];
    float* out = (float*)d_out;
    float* ws  = (float*)d_ws;   // needs 6.44 MB

    // K1: 62 chunk-blocks*16 + 64 homogeneous blocks
    k1_particular<<<dim3(62 * 16 + 64), dim3(256), 0, stream>>>(phi, theta, icept, sigma, noise, ws);
    // K2: per-series scan (64 CUs, 4-deep prefetch)
    k2_scan<<<dim3(64), dim3(64), 0, stream>>>(ws);
    // K3: 63 chunks * 16 blocks
    k3_final<<<dim3(63 * 16), dim3(256), 0, stream>>>(phi, theta, icept, sigma, noise, dvals, ws, out);
}